// Round 1
// baseline (923.900 us; speedup 1.0000x reference)
//
#include <hip/hip_runtime.h>
#include <math.h>

#define CCH   128        // C
#define C2    64         // C/2
#define C2X   256        // 2C
#define CR    8          // C/16
#define HW    16384
#define NB    16
#define EPSB  1e-5f

// workspace layout (float offsets)
#define WS_POOLED 0          // 4096
#define WS_WCH    4096       // 2048
#define WS_AVGS   6144       // 2048
#define WS_MAXB   8192       // 2048 (uint bits)
#define WS_CA     10240      // 2048
#define WS_BC     12288      // 128
#define WS_WV     16384      // 262144
#define WS_WI     278528     // 262144
#define WS_SPMEAN 540672     // 262144
#define WS_SPMAX  802816     // 262144
#define WS_SA     1064960    // 262144  (end: 1327104 floats = 5.06 MB)

__device__ __forceinline__ float sigmoidf_(float x) {
    return 1.0f / (1.0f + __expf(-x));
}

// ---------------------------------------------------------------- init
__global__ void k_init(float* p) {
    int i = blockIdx.x * 256 + threadIdx.x;   // 4096 entries: avgsum + maxbits
    p[i] = 0.0f;
}

// ---------------------------------------------------------------- global mean pool of [f_vi, f_ir]
__global__ void k_pool(const float* __restrict__ fvi, const float* __restrict__ fir,
                       float* __restrict__ pooled) {
    int b  = blockIdx.x;            // n*256 + ch
    int n  = b >> 8;
    int ch = b & 255;
    const float* src = (ch < CCH) ? (fvi + ((size_t)n * CCH + ch) * HW)
                                  : (fir + ((size_t)n * CCH + (ch - CCH)) * HW);
    const float4* s4 = (const float4*)src;
    float sum = 0.f;
    for (int i = threadIdx.x; i < HW / 4; i += 256) {
        float4 v = s4[i];
        sum += (v.x + v.y) + (v.z + v.w);
    }
    #pragma unroll
    for (int off = 32; off > 0; off >>= 1) sum += __shfl_down(sum, off, 64);
    __shared__ float r[4];
    if ((threadIdx.x & 63) == 0) r[threadIdx.x >> 6] = sum;
    __syncthreads();
    if (threadIdx.x == 0)
        pooled[b] = (r[0] + r[1] + r[2] + r[3]) * (1.0f / HW);
}

// ---------------------------------------------------------------- channel-attention MLP -> wch
__global__ void k_wch(const float* __restrict__ pooled,
                      const float* __restrict__ ca1_w, const float* __restrict__ ca1_b,
                      const float* __restrict__ ag, const float* __restrict__ ab,
                      const float* __restrict__ am, const float* __restrict__ av,
                      const float* __restrict__ ca2_w, const float* __restrict__ ca2_b,
                      const float* __restrict__ bg, const float* __restrict__ bb,
                      const float* __restrict__ bm, const float* __restrict__ bv,
                      float* __restrict__ wch) {
    int n = blockIdx.x;
    int t = threadIdx.x;            // 128 threads
    __shared__ float h[C2];
    if (t < C2) {
        float acc = ca1_b[t];
        const float* w = ca1_w + t * C2X;
        const float* p = pooled + n * C2X;
        for (int k = 0; k < C2X; k++) acc += w[k] * p[k];
        float s = ag[t] * rsqrtf(av[t] + EPSB);
        acc = (acc - am[t]) * s + ab[t];
        h[t] = fmaxf(acc, 0.f);
    }
    __syncthreads();
    float acc = ca2_b[t];
    const float* w = ca2_w + t * C2;
    for (int j = 0; j < C2; j++) acc += w[j] * h[j];
    float s = bg[t] * rsqrtf(bv[t] + EPSB);
    acc = (acc - bm[t]) * s + bb[t];
    wch[n * CCH + t] = sigmoidf_(acc);
}

// ---------------------------------------------------------------- fold bn_c into conv bias
__global__ void k_mkbias(const float* __restrict__ conv1_b,
                         const float* __restrict__ cg, const float* __restrict__ cb,
                         const float* __restrict__ cm, const float* __restrict__ cv,
                         float* __restrict__ Bc) {
    int o = threadIdx.x;
    float A = cg[o] * rsqrtf(cv[o] + EPSB);
    Bc[o] = A * (conv1_b[o] - cm[o]) + cb[o];
}

// ---------------------------------------------------------------- per-batch effective conv weights
// Wv[n][c][o] = A[o]*(W[o][c] + u[n][c]*W[o][c+C]);  Wi[n][c][o] = A[o]*(W[o][c+C] + u[n][c]*W[o][c])
__global__ void k_mkweights(const float* __restrict__ wch, const float* __restrict__ conv1_w,
                            const float* __restrict__ cg, const float* __restrict__ cv,
                            float* __restrict__ Wv, float* __restrict__ Wi) {
    int b = blockIdx.x;             // n*C + c
    int c = b & 127;
    int o = threadIdx.x;            // 128
    float A  = cg[o] * rsqrtf(cv[o] + EPSB);
    float u  = wch[b];              // wch[n*C+c] == wch[b]
    float w0 = conv1_w[o * C2X + c];
    float w1 = conv1_w[o * C2X + c + CCH];
    Wv[(size_t)b * CCH + o] = A * (w0 + u * w1);
    Wi[(size_t)b * CCH + o] = A * (w1 + u * w0);
}

// ---------------------------------------------------------------- fused conv1x1+bn+relu + all reductions
// block: 256 threads = 16 o-groups x 16 p-groups; tile = 128 o x 128 pixels; K = 128 c x 2 inputs
#define TP 128
#define TK 16
__global__ __launch_bounds__(256)
void k_conv_reduce(const float* __restrict__ fvi, const float* __restrict__ fir,
                   const float* __restrict__ Wv, const float* __restrict__ Wi,
                   const float* __restrict__ Bc,
                   float* __restrict__ avgsum, unsigned int* __restrict__ maxbits,
                   float* __restrict__ spmean, float* __restrict__ spmax) {
    int n  = blockIdx.x >> 7;       // 128 pixel-tiles per n
    int pt = blockIdx.x & 127;
    int p0 = pt * TP;

    __shared__ __align__(16) float sXv[TK][TP];
    __shared__ __align__(16) float sXi[TK][TP];
    __shared__ __align__(16) float sWv[TK][CCH];
    __shared__ __align__(16) float sWi[TK][CCH];

    int tid = threadIdx.x;
    int og = tid >> 4;              // 0..15, covers o = og*8..og*8+7
    int pg = tid & 15;              // 0..15, covers p = pg*8..pg*8+7

    float acc[8][8];
    #pragma unroll
    for (int a = 0; a < 8; a++)
        #pragma unroll
        for (int b = 0; b < 8; b++) acc[a][b] = 0.f;

    const float* pv  = fvi + (size_t)n * CCH * HW + p0;
    const float* pi  = fir + (size_t)n * CCH * HW + p0;
    const float* wvp = Wv + (size_t)n * CCH * CCH;
    const float* wip = Wi + (size_t)n * CCH * CCH;

    for (int c0 = 0; c0 < CCH; c0 += TK) {
        __syncthreads();
        #pragma unroll
        for (int k = 0; k < 2; k++) {
            int i  = tid + k * 256;         // 0..511 float4 slots
            int cc = i >> 5;                // row (16 rows x 32 float4)
            int px = i & 31;
            float4 v;
            v = *(const float4*)(pv + (size_t)(c0 + cc) * HW + px * 4);
            *(float4*)&sXv[cc][px * 4] = v;
            v = *(const float4*)(pi + (size_t)(c0 + cc) * HW + px * 4);
            *(float4*)&sXi[cc][px * 4] = v;
            v = *(const float4*)(wvp + (size_t)(c0 + cc) * CCH + px * 4);
            *(float4*)&sWv[cc][px * 4] = v;
            v = *(const float4*)(wip + (size_t)(c0 + cc) * CCH + px * 4);
            *(float4*)&sWi[cc][px * 4] = v;
        }
        __syncthreads();
        #pragma unroll
        for (int cc = 0; cc < TK; cc++) {
            float wv[8], wi[8], xv[8], xi[8];
            *(float4*)&wv[0] = *(float4*)&sWv[cc][og * 8];
            *(float4*)&wv[4] = *(float4*)&sWv[cc][og * 8 + 4];
            *(float4*)&wi[0] = *(float4*)&sWi[cc][og * 8];
            *(float4*)&wi[4] = *(float4*)&sWi[cc][og * 8 + 4];
            *(float4*)&xv[0] = *(float4*)&sXv[cc][pg * 8];
            *(float4*)&xv[4] = *(float4*)&sXv[cc][pg * 8 + 4];
            *(float4*)&xi[0] = *(float4*)&sXi[cc][pg * 8];
            *(float4*)&xi[4] = *(float4*)&sXi[cc][pg * 8 + 4];
            #pragma unroll
            for (int oi = 0; oi < 8; oi++)
                #pragma unroll
                for (int pi2 = 0; pi2 < 8; pi2++)
                    acc[oi][pi2] += wv[oi] * xv[pi2] + wi[oi] * xi[pi2];
        }
    }

    // epilogue: g = relu(acc + Bc[o]); reduce per-o (sum,max over pixels) and per-p (sum,max over o)
    float bco[8];
    #pragma unroll
    for (int oi = 0; oi < 8; oi++) bco[oi] = Bc[og * 8 + oi];

    float osum[8], omax[8], psum[8], pmax[8];
    #pragma unroll
    for (int i = 0; i < 8; i++) { osum[i] = 0.f; omax[i] = 0.f; psum[i] = 0.f; pmax[i] = 0.f; }
    #pragma unroll
    for (int oi = 0; oi < 8; oi++)
        #pragma unroll
        for (int pi2 = 0; pi2 < 8; pi2++) {
            float g = fmaxf(acc[oi][pi2] + bco[oi], 0.f);
            osum[oi] += g;  omax[oi] = fmaxf(omax[oi], g);
            psum[pi2] += g; pmax[pi2] = fmaxf(pmax[pi2], g);
        }

    __syncthreads();   // done reading staged tiles; reuse sXv/sXi as [16][128] reduce buffers
    #pragma unroll
    for (int oi = 0; oi < 8; oi++) { sXv[pg][og * 8 + oi] = osum[oi]; sXi[pg][og * 8 + oi] = omax[oi]; }
    __syncthreads();
    if (tid < CCH) {
        float s = 0.f, m = 0.f;
        #pragma unroll
        for (int r = 0; r < 16; r++) { s += sXv[r][tid]; m = fmaxf(m, sXi[r][tid]); }
        atomicAdd(&avgsum[n * CCH + tid], s);
        atomicMax(&maxbits[n * CCH + tid], __float_as_uint(m));   // g >= 0: uint order == float order
    }
    __syncthreads();
    #pragma unroll
    for (int pi2 = 0; pi2 < 8; pi2++) { sXv[og][pg * 8 + pi2] = psum[pi2]; sXi[og][pg * 8 + pi2] = pmax[pi2]; }
    __syncthreads();
    if (tid < TP) {
        float s = 0.f, m = 0.f;
        #pragma unroll
        for (int r = 0; r < 16; r++) { s += sXv[r][tid]; m = fmaxf(m, sXi[r][tid]); }
        spmean[(size_t)n * HW + p0 + tid] = s * (1.0f / CCH);
        spmax [(size_t)n * HW + p0 + tid] = m;
    }
}

// ---------------------------------------------------------------- channel attention (CBAM-style MLP)
__global__ void k_ca(const float* __restrict__ avgsum, const unsigned int* __restrict__ maxbits,
                     const float* __restrict__ w1, const float* __restrict__ w2,
                     float* __restrict__ ca) {
    int n = blockIdx.x;
    int t = threadIdx.x;            // 128
    __shared__ float tsum[CR];
    if (t < CR) {
        float a = 0.f, m = 0.f;
        const float* w = w1 + t * CCH;
        for (int c = 0; c < CCH; c++) {
            a += w[c] * (avgsum[n * CCH + c] * (1.0f / HW));
            m += w[c] * __uint_as_float(maxbits[n * CCH + c]);
        }
        tsum[t] = fmaxf(a, 0.f) + fmaxf(m, 0.f);
    }
    __syncthreads();
    float s = 0.f;
    #pragma unroll
    for (int j = 0; j < CR; j++) s += w2[t * CR + j] * tsum[j];
    ca[n * CCH + t] = sigmoidf_(s);
}

// ---------------------------------------------------------------- 7x7 spatial-attention conv
__global__ void k_sa(const float* __restrict__ spmean, const float* __restrict__ spmax,
                     const float* __restrict__ sw, float* __restrict__ sa) {
    int b = blockIdx.x;             // n*128 + y
    int n = b >> 7, y = b & 127;
    int x = threadIdx.x;            // 128
    float acc = 0.f;
    for (int dy = -3; dy <= 3; dy++) {
        int yy = y + dy;
        if ((unsigned)yy >= 128u) continue;
        const float* rm = spmean + (size_t)n * HW + yy * 128;
        const float* rx = spmax  + (size_t)n * HW + yy * 128;
        #pragma unroll
        for (int dx = -3; dx <= 3; dx++) {
            int xx = x + dx;
            if ((unsigned)xx < 128u) {
                float wm = sw[(dy + 3) * 7 + (dx + 3)];
                float wx = sw[49 + (dy + 3) * 7 + (dx + 3)];
                acc += wm * rm[xx] + wx * rx[xx];
            }
        }
    }
    sa[(size_t)n * HW + y * 128 + x] = sigmoidf_(acc);
}

// ---------------------------------------------------------------- final blend
__global__ void k_out(const float4* __restrict__ fvi, const float4* __restrict__ fir,
                      const float* __restrict__ wch, const float* __restrict__ ca,
                      const float4* __restrict__ sa, float4* __restrict__ out) {
    size_t idx = (size_t)blockIdx.x * 256 + threadIdx.x;   // over N*C*HW/4
    int p4 = idx & 4095;            // HW/4 - 1
    int nc = idx >> 12;
    int n  = nc >> 7;
    float u  = wch[nc];
    float cv = ca[nc];
    float4 a = fvi[idx], b = fir[idx];
    float4 s = sa[(size_t)n * 4096 + p4];
    float4 o;
    {
        float w = sigmoidf_(s.x * cv);
        o.x = w * (b.x * u + a.x) + (1.f - w) * (a.x * u + b.x);
    }
    {
        float w = sigmoidf_(s.y * cv);
        o.y = w * (b.y * u + a.y) + (1.f - w) * (a.y * u + b.y);
    }
    {
        float w = sigmoidf_(s.z * cv);
        o.z = w * (b.z * u + a.z) + (1.f - w) * (a.z * u + b.z);
    }
    {
        float w = sigmoidf_(s.w * cv);
        o.w = w * (b.w * u + a.w) + (1.f - w) * (a.w * u + b.w);
    }
    out[idx] = o;
}

// ----------------------------------------------------------------
extern "C" void kernel_launch(void* const* d_in, const int* in_sizes, int n_in,
                              void* d_out, int out_size, void* d_ws, size_t ws_size,
                              hipStream_t stream) {
    const float* fvi     = (const float*)d_in[0];
    const float* fir     = (const float*)d_in[1];
    const float* ca1_w   = (const float*)d_in[2];
    const float* ca1_b   = (const float*)d_in[3];
    const float* bn_a_g  = (const float*)d_in[4];
    const float* bn_a_b  = (const float*)d_in[5];
    const float* bn_a_m  = (const float*)d_in[6];
    const float* bn_a_v  = (const float*)d_in[7];
    const float* ca2_w   = (const float*)d_in[8];
    const float* ca2_b   = (const float*)d_in[9];
    const float* bn_b_g  = (const float*)d_in[10];
    const float* bn_b_b  = (const float*)d_in[11];
    const float* bn_b_m  = (const float*)d_in[12];
    const float* bn_b_v  = (const float*)d_in[13];
    const float* conv1_w = (const float*)d_in[14];
    const float* conv1_b = (const float*)d_in[15];
    const float* bn_c_g  = (const float*)d_in[16];
    const float* bn_c_b  = (const float*)d_in[17];
    const float* bn_c_m  = (const float*)d_in[18];
    const float* bn_c_v  = (const float*)d_in[19];
    const float* chatt_w1 = (const float*)d_in[20];
    const float* chatt_w2 = (const float*)d_in[21];
    const float* sa_w     = (const float*)d_in[22];

    float* ws = (float*)d_ws;
    float* out = (float*)d_out;

    k_init<<<16, 256, 0, stream>>>(ws + WS_AVGS);                  // zero avgsum + maxbits (adjacent)
    k_pool<<<NB * C2X, 256, 0, stream>>>(fvi, fir, ws + WS_POOLED);
    k_wch<<<NB, 128, 0, stream>>>(ws + WS_POOLED, ca1_w, ca1_b,
                                  bn_a_g, bn_a_b, bn_a_m, bn_a_v,
                                  ca2_w, ca2_b, bn_b_g, bn_b_b, bn_b_m, bn_b_v,
                                  ws + WS_WCH);
    k_mkbias<<<1, 128, 0, stream>>>(conv1_b, bn_c_g, bn_c_b, bn_c_m, bn_c_v, ws + WS_BC);
    k_mkweights<<<NB * CCH, 128, 0, stream>>>(ws + WS_WCH, conv1_w, bn_c_g, bn_c_v,
                                              ws + WS_WV, ws + WS_WI);
    k_conv_reduce<<<NB * (HW / TP), 256, 0, stream>>>(fvi, fir, ws + WS_WV, ws + WS_WI, ws + WS_BC,
                                                      ws + WS_AVGS, (unsigned int*)(ws + WS_MAXB),
                                                      ws + WS_SPMEAN, ws + WS_SPMAX);
    k_ca<<<NB, 128, 0, stream>>>(ws + WS_AVGS, (const unsigned int*)(ws + WS_MAXB),
                                 chatt_w1, chatt_w2, ws + WS_CA);
    k_sa<<<NB * 128, 128, 0, stream>>>(ws + WS_SPMEAN, ws + WS_SPMAX, sa_w, ws + WS_SA);
    k_out<<<(NB * CCH * HW / 4) / 256, 256, 0, stream>>>((const float4*)fvi, (const float4*)fir,
                                                         ws + WS_WCH, ws + WS_CA,
                                                         (const float4*)(ws + WS_SA), (float4*)out);
}

// Round 2
// 518.929 us; speedup vs baseline: 1.7804x; 1.7804x over previous
//
#include <hip/hip_runtime.h>
#include <math.h>

#define CCH   128        // C
#define C2    64         // C/2
#define C2X   256        // 2C
#define CR    8          // C/16
#define HW    16384
#define NB    16
#define EPSB  1e-5f

// workspace layout (float offsets)
#define WS_POOLED 0          // 4096
#define WS_WCH    4096       // 2048
#define WS_AVGS   6144       // 2048
#define WS_MAXB   8192       // 2048 (uint bits)
#define WS_CA     10240      // 2048
#define WS_BC     12288      // 128
#define WS_WV     16384      // 131072 floats worth (262144 bf16)  [n][o][c]
#define WS_WI     147456     // 131072
#define WS_SPMEAN 278528     // 262144
#define WS_SPMAX  540672     // 262144
#define WS_SA     802816     // 262144  (end: 1064960 floats = 4.06 MB)

typedef short short8 __attribute__((ext_vector_type(8)));
typedef float floatx4 __attribute__((ext_vector_type(4)));
typedef unsigned short ushort_t;
typedef unsigned int uint_t;

__device__ __forceinline__ float sigmoidf_(float x) {
    return 1.0f / (1.0f + __expf(-x));
}

// fp32 -> bf16 with round-to-nearest-even
__device__ __forceinline__ uint_t f2bf(float f) {
    uint_t u = __float_as_uint(f);
    return (u + 0x7FFFu + ((u >> 16) & 1u)) >> 16;
}
__device__ __forceinline__ uint_t pack2bf(float a, float b) {
    return f2bf(a) | (f2bf(b) << 16);
}

// ---------------------------------------------------------------- global mean pool of [f_vi, f_ir]
__global__ void k_pool(const float* __restrict__ fvi, const float* __restrict__ fir,
                       float* __restrict__ pooled) {
    int b  = blockIdx.x;            // n*256 + ch
    int n  = b >> 8;
    int ch = b & 255;
    const float* src = (ch < CCH) ? (fvi + ((size_t)n * CCH + ch) * HW)
                                  : (fir + ((size_t)n * CCH + (ch - CCH)) * HW);
    const float4* s4 = (const float4*)src;
    float sum = 0.f;
    for (int i = threadIdx.x; i < HW / 4; i += 256) {
        float4 v = s4[i];
        sum += (v.x + v.y) + (v.z + v.w);
    }
    #pragma unroll
    for (int off = 32; off > 0; off >>= 1) sum += __shfl_down(sum, off, 64);
    __shared__ float r[4];
    if ((threadIdx.x & 63) == 0) r[threadIdx.x >> 6] = sum;
    __syncthreads();
    if (threadIdx.x == 0)
        pooled[b] = (r[0] + r[1] + r[2] + r[3]) * (1.0f / HW);
}

// ---------------------------------------------------------------- channel-attention MLP -> wch
__global__ void k_wch(const float* __restrict__ pooled,
                      const float* __restrict__ ca1_w, const float* __restrict__ ca1_b,
                      const float* __restrict__ ag, const float* __restrict__ ab,
                      const float* __restrict__ am, const float* __restrict__ av,
                      const float* __restrict__ ca2_w, const float* __restrict__ ca2_b,
                      const float* __restrict__ bg, const float* __restrict__ bb,
                      const float* __restrict__ bm, const float* __restrict__ bv,
                      float* __restrict__ wch) {
    int n = blockIdx.x;
    int t = threadIdx.x;            // 128 threads
    __shared__ float h[C2];
    if (t < C2) {
        float acc = ca1_b[t];
        const float* w = ca1_w + t * C2X;
        const float* p = pooled + n * C2X;
        for (int k = 0; k < C2X; k++) acc += w[k] * p[k];
        float s = ag[t] * rsqrtf(av[t] + EPSB);
        acc = (acc - am[t]) * s + ab[t];
        h[t] = fmaxf(acc, 0.f);
    }
    __syncthreads();
    float acc = ca2_b[t];
    const float* w = ca2_w + t * C2;
    for (int j = 0; j < C2; j++) acc += w[j] * h[j];
    float s = bg[t] * rsqrtf(bv[t] + EPSB);
    acc = (acc - bm[t]) * s + bb[t];
    wch[n * CCH + t] = sigmoidf_(acc);
}

// ---------------------------------------------------------------- per-batch effective bf16 conv weights
// Wv[n][o][c] = bf16( A[o]*(W[o][c] + u[n][c]*W[o][c+C]) ), Wi = swap.  Also folds:
// zeroing of avgsum/maxbits (blocks 0..15) and the bn_c-folded bias (block 16).
__global__ void k_mkweights(const float* __restrict__ wch, const float* __restrict__ conv1_w,
                            const float* __restrict__ cg, const float* __restrict__ cb,
                            const float* __restrict__ cm, const float* __restrict__ cv,
                            const float* __restrict__ conv1_b,
                            ushort_t* __restrict__ Wv, ushort_t* __restrict__ Wi,
                            float* __restrict__ Bc, float* __restrict__ zeroreg) {
    int b = blockIdx.x;             // n*128 + o
    int t = threadIdx.x;            // 128 = c
    if (b < 16) { zeroreg[b * 256 + t] = 0.f; zeroreg[b * 256 + 128 + t] = 0.f; }
    if (b == 16) {
        float A = cg[t] * rsqrtf(cv[t] + EPSB);
        Bc[t] = A * (conv1_b[t] - cm[t]) + cb[t];
    }
    int n = b >> 7, o = b & 127;
    float A  = cg[o] * rsqrtf(cv[o] + EPSB);
    float u  = wch[n * CCH + t];
    float w0 = conv1_w[o * C2X + t];
    float w1 = conv1_w[o * C2X + t + CCH];
    Wv[(size_t)b * CCH + t] = (ushort_t)f2bf(A * (w0 + u * w1));
    Wi[(size_t)b * CCH + t] = (ushort_t)f2bf(A * (w1 + u * w0));
}

// ---------------------------------------------------------------- fused conv1x1+bn+relu + reductions (MFMA)
// grid: 16 n x 128 p-tiles; block: 256 threads = 4 waves
// tile: 128 o x 128 p; K-loop: c0 in {0,32,64,96}, 2 streams (vi, ir)
// wave w computes o in [w*32, w*32+32): 2 o-tiles x 8 p-tiles of 16x16 MFMA
#define XROW 40   // LDS row stride in bf16 elems (80 B, 16B-aligned, bank-friendly)
__global__ __launch_bounds__(256)
void k_conv_reduce(const float* __restrict__ fvi, const float* __restrict__ fir,
                   const ushort_t* __restrict__ Wv, const ushort_t* __restrict__ Wi,
                   const float* __restrict__ Bc,
                   float* __restrict__ avgsum, uint_t* __restrict__ maxbits,
                   float* __restrict__ spmean, float* __restrict__ spmax) {
    int n  = blockIdx.x >> 7;
    int pt = blockIdx.x & 127;
    int p0 = pt * 128;

    __shared__ __align__(16) ushort_t sXv[128 * XROW];   // x_vi tile transposed: [p][c] bf16
    __shared__ __align__(16) ushort_t sXi[128 * XROW];
    __shared__ __align__(16) ushort_t sWv[128 * XROW];   // W tiles: [o][c] bf16
    __shared__ __align__(16) ushort_t sWi[128 * XROW];

    int tid  = threadIdx.x;
    int wave = tid >> 6;
    int lane = tid & 63;
    int q    = lane >> 4;       // 0..3
    int ln   = lane & 15;

    floatx4 acc[2][8];
    #pragma unroll
    for (int a = 0; a < 2; a++)
        #pragma unroll
        for (int b = 0; b < 8; b++) acc[a][b] = (floatx4){0.f, 0.f, 0.f, 0.f};

    const float* pv = fvi + (size_t)n * CCH * HW + p0;
    const float* pi = fir + (size_t)n * CCH * HW + p0;
    const ushort_t* wvb = Wv + (size_t)n * CCH * CCH;
    const ushort_t* wib = Wi + (size_t)n * CCH * CCH;

    for (int c0 = 0; c0 < CCH; c0 += 32) {
        __syncthreads();
        // --- stage W tiles: 128 o x 32 c bf16, straight copy (16B chunks)
        #pragma unroll
        for (int s = 0; s < 2; ++s) {
            int i  = tid + s * 256;       // 0..511
            int o  = i >> 2;
            int ch = i & 3;
            *(uint4*)&sWv[o * XROW + ch * 8] =
                *(const uint4*)&wvb[(size_t)o * CCH + c0 + ch * 8];
            *(uint4*)&sWi[o * XROW + ch * 8] =
                *(const uint4*)&wib[(size_t)o * CCH + c0 + ch * 8];
        }
        // --- stage X tiles: 32 c x 128 p fp32 -> bf16, transposed to [p][c]
        #pragma unroll
        for (int it = 0; it < 8; ++it) {
            int i  = it * 256 + tid;
            int p  = i & 127;
            int cp = i >> 7;              // 0..15 channel-pair
            const float* s1 = pv + (size_t)(c0 + 2 * cp) * HW + p;
            *(uint_t*)&sXv[p * XROW + 2 * cp] = pack2bf(s1[0], s1[HW]);
            const float* s2 = pi + (size_t)(c0 + 2 * cp) * HW + p;
            *(uint_t*)&sXi[p * XROW + 2 * cp] = pack2bf(s2[0], s2[HW]);
        }
        __syncthreads();
        // --- MFMA: A-frag = W rows (K-contig), B-frag = x rows [p][c] (K-contig)
        short8 aV[2], aI[2];
        #pragma unroll
        for (int ot = 0; ot < 2; ++ot) {
            int row = wave * 32 + ot * 16 + ln;
            aV[ot] = *(const short8*)&sWv[row * XROW + q * 8];
            aI[ot] = *(const short8*)&sWi[row * XROW + q * 8];
        }
        #pragma unroll
        for (int pj = 0; pj < 8; ++pj) {
            int row = pj * 16 + ln;
            short8 bV = *(const short8*)&sXv[row * XROW + q * 8];
            short8 bI = *(const short8*)&sXi[row * XROW + q * 8];
            #pragma unroll
            for (int ot = 0; ot < 2; ++ot) {
                acc[ot][pj] = __builtin_amdgcn_mfma_f32_16x16x32_bf16(aV[ot], bV, acc[ot][pj], 0, 0, 0);
                acc[ot][pj] = __builtin_amdgcn_mfma_f32_16x16x32_bf16(aI[ot], bI, acc[ot][pj], 0, 0, 0);
            }
        }
    }

    // --- epilogue: g = relu(acc + Bc[o]); C/D layout: col = ln (p), row = q*4+r (o within 16)
    float bc[2][4];
    #pragma unroll
    for (int ot = 0; ot < 2; ++ot)
        #pragma unroll
        for (int r = 0; r < 4; ++r)
            bc[ot][r] = Bc[wave * 32 + ot * 16 + q * 4 + r];

    float rs[2][4], rm[2][4], ps[8], pm[8];
    #pragma unroll
    for (int ot = 0; ot < 2; ++ot)
        #pragma unroll
        for (int r = 0; r < 4; ++r) { rs[ot][r] = 0.f; rm[ot][r] = 0.f; }
    #pragma unroll
    for (int pj = 0; pj < 8; ++pj) { ps[pj] = 0.f; pm[pj] = 0.f; }

    #pragma unroll
    for (int ot = 0; ot < 2; ++ot)
        #pragma unroll
        for (int pj = 0; pj < 8; ++pj) {
            floatx4 a = acc[ot][pj];
            #pragma unroll
            for (int r = 0; r < 4; ++r) {
                float g = fmaxf(a[r] + bc[ot][r], 0.f);
                rs[ot][r] += g;
                rm[ot][r] = fmaxf(rm[ot][r], g);
                ps[pj] += g;
                pm[pj] = fmaxf(pm[pj], g);
            }
        }

    // per-o: reduce over the 16 lanes of each quad (cols) -> atomics
    #pragma unroll
    for (int ot = 0; ot < 2; ++ot)
        #pragma unroll
        for (int r = 0; r < 4; ++r)
            #pragma unroll
            for (int off = 1; off < 16; off <<= 1) {
                rs[ot][r] += __shfl_xor(rs[ot][r], off, 64);
                rm[ot][r] = fmaxf(rm[ot][r], __shfl_xor(rm[ot][r], off, 64));
            }
    if (ln == 0) {
        #pragma unroll
        for (int ot = 0; ot < 2; ++ot)
            #pragma unroll
            for (int r = 0; r < 4; ++r) {
                int o = wave * 32 + ot * 16 + q * 4 + r;
                atomicAdd(&avgsum[n * CCH + o], rs[ot][r]);
                atomicMax(&maxbits[n * CCH + o], __float_as_uint(rm[ot][r]));  // g >= 0
            }
    }

    // per-p: reduce over q (rows within wave), then across waves via LDS
    #pragma unroll
    for (int pj = 0; pj < 8; ++pj) {
        #pragma unroll
        for (int off = 16; off < 64; off <<= 1) {
            ps[pj] += __shfl_xor(ps[pj], off, 64);
            pm[pj] = fmaxf(pm[pj], __shfl_xor(pm[pj], off, 64));
        }
    }
    __syncthreads();                       // done reading staged tiles
    float* redS = (float*)sXv;             // [4 waves][128 p]
    float* redM = (float*)sXi;
    if (lane < 16) {
        #pragma unroll
        for (int pj = 0; pj < 8; ++pj) {
            redS[wave * 128 + pj * 16 + ln] = ps[pj];
            redM[wave * 128 + pj * 16 + ln] = pm[pj];
        }
    }
    __syncthreads();
    if (tid < 128) {
        float s = 0.f, m = 0.f;
        #pragma unroll
        for (int w = 0; w < 4; ++w) {
            s += redS[w * 128 + tid];
            m = fmaxf(m, redM[w * 128 + tid]);
        }
        spmean[(size_t)n * HW + p0 + tid] = s * (1.0f / CCH);
        spmax [(size_t)n * HW + p0 + tid] = m;
    }
}

// ---------------------------------------------------------------- channel attention (CBAM-style MLP)
__global__ void k_ca(const float* __restrict__ avgsum, const uint_t* __restrict__ maxbits,
                     const float* __restrict__ w1, const float* __restrict__ w2,
                     float* __restrict__ ca) {
    int n = blockIdx.x;
    int t = threadIdx.x;            // 128
    __shared__ float tsum[CR];
    if (t < CR) {
        float a = 0.f, m = 0.f;
        const float* w = w1 + t * CCH;
        for (int c = 0; c < CCH; c++) {
            a += w[c] * (avgsum[n * CCH + c] * (1.0f / HW));
            m += w[c] * __uint_as_float(maxbits[n * CCH + c]);
        }
        tsum[t] = fmaxf(a, 0.f) + fmaxf(m, 0.f);
    }
    __syncthreads();
    float s = 0.f;
    #pragma unroll
    for (int j = 0; j < CR; j++) s += w2[t * CR + j] * tsum[j];
    ca[n * CCH + t] = sigmoidf_(s);
}

// ---------------------------------------------------------------- 7x7 spatial-attention conv
__global__ void k_sa(const float* __restrict__ spmean, const float* __restrict__ spmax,
                     const float* __restrict__ sw, float* __restrict__ sa) {
    int b = blockIdx.x;             // n*128 + y
    int n = b >> 7, y = b & 127;
    int x = threadIdx.x;            // 128
    float acc = 0.f;
    for (int dy = -3; dy <= 3; dy++) {
        int yy = y + dy;
        if ((unsigned)yy >= 128u) continue;
        const float* rm = spmean + (size_t)n * HW + yy * 128;
        const float* rx = spmax  + (size_t)n * HW + yy * 128;
        #pragma unroll
        for (int dx = -3; dx <= 3; dx++) {
            int xx = x + dx;
            if ((unsigned)xx < 128u) {
                float wm = sw[(dy + 3) * 7 + (dx + 3)];
                float wx = sw[49 + (dy + 3) * 7 + (dx + 3)];
                acc += wm * rm[xx] + wx * rx[xx];
            }
        }
    }
    sa[(size_t)n * HW + y * 128 + x] = sigmoidf_(acc);
}

// ---------------------------------------------------------------- final blend
__global__ void k_out(const float4* __restrict__ fvi, const float4* __restrict__ fir,
                      const float* __restrict__ wch, const float* __restrict__ ca,
                      const float4* __restrict__ sa, float4* __restrict__ out) {
    size_t idx = (size_t)blockIdx.x * 256 + threadIdx.x;   // over N*C*HW/4
    int p4 = idx & 4095;            // HW/4 - 1
    int nc = idx >> 12;
    int n  = nc >> 7;
    float u  = wch[nc];
    float cv = ca[nc];
    float4 a = fvi[idx], b = fir[idx];
    float4 s = sa[(size_t)n * 4096 + p4];
    float4 o;
    {
        float w = sigmoidf_(s.x * cv);
        o.x = w * (b.x * u + a.x) + (1.f - w) * (a.x * u + b.x);
    }
    {
        float w = sigmoidf_(s.y * cv);
        o.y = w * (b.y * u + a.y) + (1.f - w) * (a.y * u + b.y);
    }
    {
        float w = sigmoidf_(s.z * cv);
        o.z = w * (b.z * u + a.z) + (1.f - w) * (a.z * u + b.z);
    }
    {
        float w = sigmoidf_(s.w * cv);
        o.w = w * (b.w * u + a.w) + (1.f - w) * (a.w * u + b.w);
    }
    out[idx] = o;
}

// ----------------------------------------------------------------
extern "C" void kernel_launch(void* const* d_in, const int* in_sizes, int n_in,
                              void* d_out, int out_size, void* d_ws, size_t ws_size,
                              hipStream_t stream) {
    const float* fvi     = (const float*)d_in[0];
    const float* fir     = (const float*)d_in[1];
    const float* ca1_w   = (const float*)d_in[2];
    const float* ca1_b   = (const float*)d_in[3];
    const float* bn_a_g  = (const float*)d_in[4];
    const float* bn_a_b  = (const float*)d_in[5];
    const float* bn_a_m  = (const float*)d_in[6];
    const float* bn_a_v  = (const float*)d_in[7];
    const float* ca2_w   = (const float*)d_in[8];
    const float* ca2_b   = (const float*)d_in[9];
    const float* bn_b_g  = (const float*)d_in[10];
    const float* bn_b_b  = (const float*)d_in[11];
    const float* bn_b_m  = (const float*)d_in[12];
    const float* bn_b_v  = (const float*)d_in[13];
    const float* conv1_w = (const float*)d_in[14];
    const float* conv1_b = (const float*)d_in[15];
    const float* bn_c_g  = (const float*)d_in[16];
    const float* bn_c_b  = (const float*)d_in[17];
    const float* bn_c_m  = (const float*)d_in[18];
    const float* bn_c_v  = (const float*)d_in[19];
    const float* chatt_w1 = (const float*)d_in[20];
    const float* chatt_w2 = (const float*)d_in[21];
    const float* sa_w     = (const float*)d_in[22];

    float* ws = (float*)d_ws;
    float* out = (float*)d_out;

    k_pool<<<NB * C2X, 256, 0, stream>>>(fvi, fir, ws + WS_POOLED);
    k_wch<<<NB, 128, 0, stream>>>(ws + WS_POOLED, ca1_w, ca1_b,
                                  bn_a_g, bn_a_b, bn_a_m, bn_a_v,
                                  ca2_w, ca2_b, bn_b_g, bn_b_b, bn_b_m, bn_b_v,
                                  ws + WS_WCH);
    k_mkweights<<<NB * CCH, 128, 0, stream>>>(ws + WS_WCH, conv1_w,
                                              bn_c_g, bn_c_b, bn_c_m, bn_c_v, conv1_b,
                                              (ushort_t*)(ws + WS_WV), (ushort_t*)(ws + WS_WI),
                                              ws + WS_BC, ws + WS_AVGS);
    k_conv_reduce<<<NB * (HW / 128), 256, 0, stream>>>(fvi, fir,
                                                       (const ushort_t*)(ws + WS_WV),
                                                       (const ushort_t*)(ws + WS_WI),
                                                       ws + WS_BC,
                                                       ws + WS_AVGS, (uint_t*)(ws + WS_MAXB),
                                                       ws + WS_SPMEAN, ws + WS_SPMAX);
    k_ca<<<NB, 128, 0, stream>>>(ws + WS_AVGS, (const uint_t*)(ws + WS_MAXB),
                                 chatt_w1, chatt_w2, ws + WS_CA);
    k_sa<<<NB * 128, 128, 0, stream>>>(ws + WS_SPMEAN, ws + WS_SPMAX, sa_w, ws + WS_SA);
    k_out<<<(NB * CCH * HW / 4) / 256, 256, 0, stream>>>((const float4*)fvi, (const float4*)fir,
                                                         ws + WS_WCH, ws + WS_CA,
                                                         (const float4*)(ws + WS_SA), (float4*)out);
}